// Round 6
// baseline (638.491 us; speedup 1.0000x reference)
//
#include <hip/hip_runtime.h>

// Problem constants: B=8, H=W=1024, V=35709, T=70789
#define BATCH 8
#define HWPIX (1024 * 1024)
#define NVERT 35709
#define NTRI  70789
#define CHUNKS 512     // chunks per batch: 512 x 2048 px = 1M px
#define QPC    512     // quads per chunk (256 threads x 2 quads)

typedef float        f32x4 __attribute__((ext_vector_type(4)));
typedef int          i32x4 __attribute__((ext_vector_type(4)));
typedef unsigned int u32x4 __attribute__((ext_vector_type(4)));

__device__ __forceinline__ unsigned q8(float x) {
    float v = x * 255.0f + 0.5f;
    v = fminf(fmaxf(v, 0.0f), 255.0f);
    return (unsigned)v;
}

// ---------------------------------------------------------------------------
// Prep stage 1: quantize per-(batch,vertex) color to RGBX u8 in one uint.
// ---------------------------------------------------------------------------
__global__ __launch_bounds__(256) void quant_colors(
    const float* __restrict__ colors,   // [B,V,3]
    unsigned*    __restrict__ ctab)     // [B,V]
{
    const int v = blockIdx.x * blockDim.x + threadIdx.x;
    const int b = blockIdx.y;
    if (v >= NVERT) return;
    const float* c = colors + ((long long)b * NVERT + v) * 3;
    ctab[b * NVERT + v] = q8(c[0]) | (q8(c[1]) << 8) | (q8(c[2]) << 16);
}

// ---------------------------------------------------------------------------
// Prep stage 2: per-(batch,triangle) record = (rgbx0, rgbx1, rgbx2, 0).
// tab: [B,T] uint4 = 9.06 MB (1.13 MB per batch -> L2-resident per XCD).
// ---------------------------------------------------------------------------
__global__ __launch_bounds__(256) void build_tab(
    const int*      __restrict__ tris,  // [T,3]
    const unsigned* __restrict__ ctab,  // [B,V]
    u32x4*          __restrict__ tab)   // [B,T]
{
    const int t = blockIdx.x * blockDim.x + threadIdx.x;
    const int b = blockIdx.y;
    if (t >= NTRI) return;
    const int v0 = tris[3 * t + 0];
    const int v1 = tris[3 * t + 1];
    const int v2 = tris[3 * t + 2];
    const unsigned* cb = ctab + b * NVERT;
    u32x4 w;
    w.x = cb[v0]; w.y = cb[v1]; w.z = cb[v2]; w.w = 0u;
    tab[(long long)b * NTRI + t] = w;
}

// ---------------------------------------------------------------------------
// Zero the 8 per-batch chunk counters (ws is re-poisoned to 0xAA each launch).
// ---------------------------------------------------------------------------
__global__ void zero_counters(unsigned* __restrict__ cnt) {
    if (threadIdx.x < BATCH) cnt[threadIdx.x] = 0u;
}

// ---------------------------------------------------------------------------
// Main: XCD-affine work-stealing. Each block reads its REAL XCD id
// (HW_REG_XCC_ID) and drains chunks of that XCD's batch first, so each XCD's
// gathers hit only its own 1.13 MB sub-table (L2-resident). After its own
// batch is empty it probes the other batches, so every chunk is processed
// regardless of block->XCD distribution (correctness never depends on it).
// Per chunk: thread = 2 quads 256 apart -> coalesced 16B/lane streams, 8
// independent uint4 gathers in flight. Stores are nontemporal (don't evict
// the table from L2); loads are cached (LLC absorbs re-reads).
// ---------------------------------------------------------------------------
__global__ __launch_bounds__(256) void raster_steal(
    const int*   __restrict__ tids,   // [B,H,W]
    const float* __restrict__ bary,   // [B,H,W,3]
    const u32x4* __restrict__ tab,    // [B,T]
    float*       __restrict__ out,    // images [B,3,H,W] ++ alphas [B,1,H,W]
    unsigned*    __restrict__ cnt)    // [8] chunk counters
{
    unsigned xcc;
    asm volatile("s_getreg_b32 %0, hwreg(HW_REG_XCC_ID)" : "=s"(xcc));
    xcc &= 7u;

    const int tid = (int)threadIdx.x;
    __shared__ unsigned sc;

    for (int bb = 0; bb < BATCH; ++bb) {
        const int b = (int)((xcc + (unsigned)bb) & 7u);
        const u32x4* tbp = tab + (long long)b * NTRI;
        float* img = out + (long long)b * (3 * HWPIX);
        float* al  = out + (long long)BATCH * 3 * HWPIX + (long long)b * HWPIX;

        for (;;) {
            if (tid == 0) sc = atomicAdd(&cnt[b], 1u);
            __syncthreads();
            const unsigned c = sc;
            __syncthreads();
            if (c >= CHUNKS) break;

            const int q0 = (int)c * QPC + tid;           // quad index in batch
            const long long qg0 = (long long)b * (HWPIX / 4) + q0;

            // Coalesced cached loads: 2 x int4 tids, 6 x float4 bary
            i32x4 t4[2];
            t4[0] = ((const i32x4*)tids)[qg0];
            t4[1] = ((const i32x4*)tids)[qg0 + 256];
            f32x4 bv[6];
#pragma unroll
            for (int u = 0; u < 2; ++u)
#pragma unroll
                for (int k = 0; k < 3; ++k)
                    bv[3 * u + k] = ((const f32x4*)bary)[(qg0 + u * 256) * 3 + k];

            // 8 independent gathers from the L2-hot sub-table
            const int tt[8] = {t4[0].x, t4[0].y, t4[0].z, t4[0].w,
                               t4[1].x, t4[1].y, t4[1].z, t4[1].w};
            u32x4 rec[8];
#pragma unroll
            for (int j = 0; j < 8; ++j) rec[j] = tbp[tt[j]];

#pragma unroll
            for (int u = 0; u < 2; ++u) {
                const f32x4 b0 = bv[3 * u + 0], b1 = bv[3 * u + 1], b2 = bv[3 * u + 2];
                const float w0[4] = {b0.x, b0.w, b1.z, b2.y};
                const float w1[4] = {b0.y, b1.x, b1.w, b2.z};
                const float w2[4] = {b0.z, b1.y, b2.x, b2.w};

                float r[4], g[4], bl[4], a[4];
#pragma unroll
                for (int i = 0; i < 4; ++i) {
                    const u32x4 w = rec[4 * u + i];
                    const float s0 = w0[i] * (1.0f / 255.0f);
                    const float s1 = w1[i] * (1.0f / 255.0f);
                    const float s2 = w2[i] * (1.0f / 255.0f);
                    r[i]  = fminf(fmaxf((float)( w.x        & 0xff) * s0 +
                                        (float)( w.y        & 0xff) * s1 +
                                        (float)( w.z        & 0xff) * s2, 0.0f), 1.0f);
                    g[i]  = fminf(fmaxf((float)((w.x >>  8) & 0xff) * s0 +
                                        (float)((w.y >>  8) & 0xff) * s1 +
                                        (float)((w.z >>  8) & 0xff) * s2, 0.0f), 1.0f);
                    bl[i] = fminf(fmaxf((float)((w.x >> 16) & 0xff) * s0 +
                                        (float)((w.y >> 16) & 0xff) * s1 +
                                        (float)((w.z >> 16) & 0xff) * s2, 0.0f), 1.0f);
                    a[i]  = fminf(fmaxf(2.0f * (w0[i] + w1[i] + w2[i]), 0.0f), 1.0f);
                }

                const long long s = q0 + u * 256;
                f32x4 vr = {r[0],  r[1],  r[2],  r[3]};
                f32x4 vg = {g[0],  g[1],  g[2],  g[3]};
                f32x4 vb = {bl[0], bl[1], bl[2], bl[3]};
                f32x4 va = {a[0],  a[1],  a[2],  a[3]};
                __builtin_nontemporal_store(vr, ((f32x4*)(img            )) + s);
                __builtin_nontemporal_store(vg, ((f32x4*)(img +     HWPIX)) + s);
                __builtin_nontemporal_store(vb, ((f32x4*)(img + 2 * HWPIX)) + s);
                __builtin_nontemporal_store(va, ((f32x4*)(al             )) + s);
            }
        }
    }
}

// ---------------------------------------------------------------------------
// Fallback: direct two-level gather (R1), used only if ws is too small.
// ---------------------------------------------------------------------------
__global__ __launch_bounds__(256) void raster_kernel(
    const int*   __restrict__ tids,
    const float* __restrict__ bary,
    const float* __restrict__ colors,
    const int*   __restrict__ tris,
    float*       __restrict__ out)
{
    const long long q  = (long long)blockIdx.x * blockDim.x + threadIdx.x;
    const long long p0 = q << 2;
    const int b  = (int)(p0 >> 20);
    const int hw = (int)(p0 & (HWPIX - 1));

    const int4 t4 = ((const int4*)tids)[q];
    const float4 bv0 = ((const float4*)bary)[q * 3 + 0];
    const float4 bv1 = ((const float4*)bary)[q * 3 + 1];
    const float4 bv2 = ((const float4*)bary)[q * 3 + 2];

    const float w0[4] = {bv0.x, bv0.w, bv1.z, bv2.y};
    const float w1[4] = {bv0.y, bv1.x, bv1.w, bv2.z};
    const float w2[4] = {bv0.z, bv1.y, bv2.x, bv2.w};
    const int  tid[4] = {t4.x, t4.y, t4.z, t4.w};

    const float* __restrict__ cb = colors + (long long)b * (3 * NVERT);

    float r[4], g[4], bl[4], a[4];
#pragma unroll
    for (int i = 0; i < 4; ++i) {
        const int t  = tid[i];
        const int v0 = tris[3 * t + 0];
        const int v1 = tris[3 * t + 1];
        const int v2 = tris[3 * t + 2];
        const float* c0 = cb + 3 * v0;
        const float* c1 = cb + 3 * v1;
        const float* c2 = cb + 3 * v2;
        const float u0 = w0[i], u1 = w1[i], u2 = w2[i];
        r[i]  = fminf(fmaxf(c0[0] * u0 + c1[0] * u1 + c2[0] * u2, 0.0f), 1.0f);
        g[i]  = fminf(fmaxf(c0[1] * u0 + c1[1] * u1 + c2[1] * u2, 0.0f), 1.0f);
        bl[i] = fminf(fmaxf(c0[2] * u0 + c1[2] * u1 + c2[2] * u2, 0.0f), 1.0f);
        a[i]  = fminf(fmaxf(2.0f * (u0 + u1 + u2), 0.0f), 1.0f);
    }

    float* img = out + (long long)b * (3 * HWPIX) + hw;
    ((float4*)(img            ))[0] = make_float4(r[0],  r[1],  r[2],  r[3]);
    ((float4*)(img +     HWPIX))[0] = make_float4(g[0],  g[1],  g[2],  g[3]);
    ((float4*)(img + 2 * HWPIX))[0] = make_float4(bl[0], bl[1], bl[2], bl[3]);

    float* al = out + (long long)BATCH * 3 * HWPIX + (long long)b * HWPIX + hw;
    ((float4*)al)[0] = make_float4(a[0], a[1], a[2], a[3]);
}

extern "C" void kernel_launch(void* const* d_in, const int* in_sizes, int n_in,
                              void* d_out, int out_size, void* d_ws, size_t ws_size,
                              hipStream_t stream) {
    const int*   tids   = (const int*)  d_in[0];
    const float* bary   = (const float*)d_in[1];
    const float* colors = (const float*)d_in[2];
    const int*   tris   = (const int*)  d_in[3];
    float*       out    = (float*)      d_out;

    const size_t tab_bytes  = (size_t)BATCH * NTRI * sizeof(u32x4);     // ~9.06 MB
    const size_t ctab_bytes = (size_t)BATCH * NVERT * sizeof(unsigned); // ~1.14 MB
    const size_t cnt_bytes  = BATCH * sizeof(unsigned);

    if (ws_size >= tab_bytes + ctab_bytes + cnt_bytes) {
        u32x4*    tab  = (u32x4*)d_ws;
        unsigned* ctab = (unsigned*)((char*)d_ws + tab_bytes);
        unsigned* cnt  = (unsigned*)((char*)d_ws + tab_bytes + ctab_bytes);

        zero_counters<<<1, 64, 0, stream>>>(cnt);

        dim3 g1((NVERT + 255) / 256, BATCH, 1);
        quant_colors<<<g1, 256, 0, stream>>>(colors, ctab);

        dim3 g2((NTRI + 255) / 256, BATCH, 1);
        build_tab<<<g2, 256, 0, stream>>>(tris, ctab, tab);

        raster_steal<<<4096, 256, 0, stream>>>(tids, bary, tab, out, cnt);
    } else {
        const int quads = (BATCH * HWPIX) / 4;
        raster_kernel<<<quads / 256, 256, 0, stream>>>(tids, bary, colors, tris, out);
    }
}

// Round 7
// 282.778 us; speedup vs baseline: 2.2579x; 2.2579x over previous
//
#include <hip/hip_runtime.h>

// Problem constants: B=8, H=W=1024, V=35709, T=70789
#define BATCH 8
#define HWPIX (1024 * 1024)
#define NVERT 35709
#define NTRI  70789

typedef float        f32x4 __attribute__((ext_vector_type(4)));
typedef int          i32x4 __attribute__((ext_vector_type(4)));
typedef unsigned int u32x4 __attribute__((ext_vector_type(4)));

__device__ __forceinline__ unsigned q8(float x) {
    float v = x * 255.0f + 0.5f;
    v = fminf(fmaxf(v, 0.0f), 255.0f);
    return (unsigned)v;
}

// ---------------------------------------------------------------------------
// Prep stage 1: quantize per-(batch,vertex) color to RGBX u8 in one uint.
// ctab: [B,V] uint = 1.14 MB.
// ---------------------------------------------------------------------------
__global__ __launch_bounds__(256) void quant_colors(
    const float* __restrict__ colors,   // [B,V,3]
    unsigned*    __restrict__ ctab)     // [B,V]
{
    const int v = blockIdx.x * blockDim.x + threadIdx.x;
    const int b = blockIdx.y;
    if (v >= NVERT) return;
    const float* c = colors + ((long long)b * NVERT + v) * 3;
    ctab[b * NVERT + v] = q8(c[0]) | (q8(c[1]) << 8) | (q8(c[2]) << 16);
}

// ---------------------------------------------------------------------------
// Prep stage 2: per-(batch,triangle) record = 3 dwords (rgbx0, rgbx1, rgbx2),
// packed at 12 B stride. tab: [B,T,3] uint = 6.8 MB (850 KB/batch, L2-hot).
// 12 B (not 16) because divergent gather cost is ~1.1 cyc per dword per CU:
// 3 slots/px instead of 4.
// ---------------------------------------------------------------------------
__global__ __launch_bounds__(256) void build_tab(
    const int*      __restrict__ tris,  // [T,3]
    const unsigned* __restrict__ ctab,  // [B,V]
    unsigned*       __restrict__ tab)   // [B,T,3]
{
    const int t = blockIdx.x * blockDim.x + threadIdx.x;
    const int b = blockIdx.y;
    if (t >= NTRI) return;
    const int v0 = tris[3 * t + 0];
    const int v1 = tris[3 * t + 1];
    const int v2 = tris[3 * t + 2];
    const unsigned* cb = ctab + b * NVERT;
    unsigned* rec = tab + ((long long)b * NTRI + t) * 3;
    rec[0] = cb[v0];
    rec[1] = cb[v1];
    rec[2] = cb[v2];
}

// ---------------------------------------------------------------------------
// Main: one thread = TWO quads (4 px each) placed 256 quads apart: streamed
// loads/stores are base + 16B*lane (full-line coalesced); 8 independent 12 B
// gathers in flight per thread. Loads cached (LLC absorbs re-reads; NT loads
// cost +50 MB FETCH, measured R5). Stores nontemporal (keep table in L2).
// ---------------------------------------------------------------------------
__global__ __launch_bounds__(256) void raster12_kernel(
    const int*      __restrict__ tids,   // [B,H,W]
    const float*    __restrict__ bary,   // [B,H,W,3]
    const unsigned* __restrict__ tab,    // [B,T,3] 12B records
    float*          __restrict__ out)    // images [B,3,H,W] ++ alphas [B,1,H,W]
{
    const int b   = blockIdx.x & 7;              // batch slice
    const int blk = blockIdx.x >> 3;             // 0..511 within batch
    const int tid = (int)threadIdx.x;
    const int q0  = blk * 512 + tid;             // quad index in batch (u=0)
    const long long qg0 = (long long)b * (HWPIX / 4) + q0;

    // Coalesced cached loads: 2 x int4 tids, 6 x float4 bary
    i32x4 t4[2];
    t4[0] = ((const i32x4*)tids)[qg0];
    t4[1] = ((const i32x4*)tids)[qg0 + 256];
    f32x4 bv[6];
#pragma unroll
    for (int u = 0; u < 2; ++u)
#pragma unroll
        for (int k = 0; k < 3; ++k)
            bv[3 * u + k] = ((const f32x4*)bary)[(qg0 + u * 256) * 3 + k];

    // 8 independent 12B gathers (3 dwords each), issued back-to-back
    const int tt[8] = {t4[0].x, t4[0].y, t4[0].z, t4[0].w,
                       t4[1].x, t4[1].y, t4[1].z, t4[1].w};
    const unsigned* tbp = tab + (long long)b * (3 * NTRI);
    uint3 rec[8];
#pragma unroll
    for (int j = 0; j < 8; ++j)
        rec[j] = *(const uint3*)(tbp + 3 * tt[j]);

    float* img = out + (long long)b * (3 * HWPIX);
    float* al  = out + (long long)BATCH * 3 * HWPIX + (long long)b * HWPIX;

#pragma unroll
    for (int u = 0; u < 2; ++u) {
        const f32x4 b0 = bv[3 * u + 0], b1 = bv[3 * u + 1], b2 = bv[3 * u + 2];
        const float w0[4] = {b0.x, b0.w, b1.z, b2.y};
        const float w1[4] = {b0.y, b1.x, b1.w, b2.z};
        const float w2[4] = {b0.z, b1.y, b2.x, b2.w};

        float r[4], g[4], bl[4], a[4];
#pragma unroll
        for (int i = 0; i < 4; ++i) {
            const uint3 w = rec[4 * u + i];
            const float s0 = w0[i] * (1.0f / 255.0f);
            const float s1 = w1[i] * (1.0f / 255.0f);
            const float s2 = w2[i] * (1.0f / 255.0f);
            r[i]  = fminf(fmaxf((float)( w.x        & 0xff) * s0 +
                                (float)( w.y        & 0xff) * s1 +
                                (float)( w.z        & 0xff) * s2, 0.0f), 1.0f);
            g[i]  = fminf(fmaxf((float)((w.x >>  8) & 0xff) * s0 +
                                (float)((w.y >>  8) & 0xff) * s1 +
                                (float)((w.z >>  8) & 0xff) * s2, 0.0f), 1.0f);
            bl[i] = fminf(fmaxf((float)((w.x >> 16) & 0xff) * s0 +
                                (float)((w.y >> 16) & 0xff) * s1 +
                                (float)((w.z >> 16) & 0xff) * s2, 0.0f), 1.0f);
            a[i]  = fminf(fmaxf(2.0f * (w0[i] + w1[i] + w2[i]), 0.0f), 1.0f);
        }

        // Coalesced nontemporal stores: float4 slot q0 + u*256 in each plane
        const long long s = q0 + u * 256;
        f32x4 vr = {r[0],  r[1],  r[2],  r[3]};
        f32x4 vg = {g[0],  g[1],  g[2],  g[3]};
        f32x4 vb = {bl[0], bl[1], bl[2], bl[3]};
        f32x4 va = {a[0],  a[1],  a[2],  a[3]};
        __builtin_nontemporal_store(vr, ((f32x4*)(img            )) + s);
        __builtin_nontemporal_store(vg, ((f32x4*)(img +     HWPIX)) + s);
        __builtin_nontemporal_store(vb, ((f32x4*)(img + 2 * HWPIX)) + s);
        __builtin_nontemporal_store(va, ((f32x4*)(al             )) + s);
    }
}

// ---------------------------------------------------------------------------
// Fallback: direct two-level gather (R1), used only if ws is too small.
// ---------------------------------------------------------------------------
__global__ __launch_bounds__(256) void raster_kernel(
    const int*   __restrict__ tids,
    const float* __restrict__ bary,
    const float* __restrict__ colors,
    const int*   __restrict__ tris,
    float*       __restrict__ out)
{
    const long long q  = (long long)blockIdx.x * blockDim.x + threadIdx.x;
    const long long p0 = q << 2;
    const int b  = (int)(p0 >> 20);
    const int hw = (int)(p0 & (HWPIX - 1));

    const int4 t4 = ((const int4*)tids)[q];
    const float4 bv0 = ((const float4*)bary)[q * 3 + 0];
    const float4 bv1 = ((const float4*)bary)[q * 3 + 1];
    const float4 bv2 = ((const float4*)bary)[q * 3 + 2];

    const float w0[4] = {bv0.x, bv0.w, bv1.z, bv2.y};
    const float w1[4] = {bv0.y, bv1.x, bv1.w, bv2.z};
    const float w2[4] = {bv0.z, bv1.y, bv2.x, bv2.w};
    const int  tid[4] = {t4.x, t4.y, t4.z, t4.w};

    const float* __restrict__ cb = colors + (long long)b * (3 * NVERT);

    float r[4], g[4], bl[4], a[4];
#pragma unroll
    for (int i = 0; i < 4; ++i) {
        const int t  = tid[i];
        const int v0 = tris[3 * t + 0];
        const int v1 = tris[3 * t + 1];
        const int v2 = tris[3 * t + 2];
        const float* c0 = cb + 3 * v0;
        const float* c1 = cb + 3 * v1;
        const float* c2 = cb + 3 * v2;
        const float u0 = w0[i], u1 = w1[i], u2 = w2[i];
        r[i]  = fminf(fmaxf(c0[0] * u0 + c1[0] * u1 + c2[0] * u2, 0.0f), 1.0f);
        g[i]  = fminf(fmaxf(c0[1] * u0 + c1[1] * u1 + c2[1] * u2, 0.0f), 1.0f);
        bl[i] = fminf(fmaxf(c0[2] * u0 + c1[2] * u1 + c2[2] * u2, 0.0f), 1.0f);
        a[i]  = fminf(fmaxf(2.0f * (u0 + u1 + u2), 0.0f), 1.0f);
    }

    float* img = out + (long long)b * (3 * HWPIX) + hw;
    ((float4*)(img            ))[0] = make_float4(r[0],  r[1],  r[2],  r[3]);
    ((float4*)(img +     HWPIX))[0] = make_float4(g[0],  g[1],  g[2],  g[3]);
    ((float4*)(img + 2 * HWPIX))[0] = make_float4(bl[0], bl[1], bl[2], bl[3]);

    float* al = out + (long long)BATCH * 3 * HWPIX + (long long)b * HWPIX + hw;
    ((float4*)al)[0] = make_float4(a[0], a[1], a[2], a[3]);
}

extern "C" void kernel_launch(void* const* d_in, const int* in_sizes, int n_in,
                              void* d_out, int out_size, void* d_ws, size_t ws_size,
                              hipStream_t stream) {
    const int*   tids   = (const int*)  d_in[0];
    const float* bary   = (const float*)d_in[1];
    const float* colors = (const float*)d_in[2];
    const int*   tris   = (const int*)  d_in[3];
    float*       out    = (float*)      d_out;

    const size_t tab_bytes  = (size_t)BATCH * NTRI * 12;                // ~6.8 MB
    const size_t ctab_bytes = (size_t)BATCH * NVERT * sizeof(unsigned); // ~1.14 MB

    if (ws_size >= tab_bytes + ctab_bytes) {
        unsigned* tab  = (unsigned*)d_ws;
        unsigned* ctab = (unsigned*)((char*)d_ws + tab_bytes);

        dim3 g1((NVERT + 255) / 256, BATCH, 1);
        quant_colors<<<g1, 256, 0, stream>>>(colors, ctab);

        dim3 g2((NTRI + 255) / 256, BATCH, 1);
        build_tab<<<g2, 256, 0, stream>>>(tris, ctab, tab);

        const int grid = (BATCH * HWPIX) / (8 * 256);   // 4096 blocks
        raster12_kernel<<<grid, 256, 0, stream>>>(tids, bary, tab, out);
    } else {
        const int quads = (BATCH * HWPIX) / 4;
        raster_kernel<<<quads / 256, 256, 0, stream>>>(tids, bary, colors, tris, out);
    }
}